// Round 16
// baseline (62.328 us; speedup 1.0000x reference)
//
#include <hip/hip_runtime.h>

// SiamFC cross-correlation: out[n,0,oh,ow] = sum_{c,i,j} x[n,c,oh+i,ow+j] * z[n,c,i,j]
// n=256, c=256, z=6x6, x=26x26, out=21x21.
//
// Round-16 = Round-15 (wave-private barrier-free pipeline) + RACE FIX:
// a single __syncthreads() after the main loop, before the reduction writes.
// (R15's bug: reduction slots alias wave-0's staging buffer; with no in-loop
// barriers, wave 1 could finish and clobber wave 0's staging mid-compute.)
//
// Structure: each wave stages ITS OWN 2 channels/round into its own LDS half
// (6 gload_lds(16B)/round) -> no cross-wave deps -> zero s_barrier in the main
// loop; per-wave counted vmcnt(6). z double-buffered in registers: z(r+1)
// issued right after the vmcnt, in flight under compute(r); FIFO order forces
// it complete by round r+1's vmcnt(6). Lane map (per wave): cc=bit0, g=bit1,
// t=bits2-4 (7 used), h=bit5. 6 splits {44,44,44,44,40,40} -> 6 blocks/CU.

#define OH 21
#define OW 21
#define WBUF 1352              // 2 ch * 676 floats (per wave, per buffer)
#define NTHREADS 128
#define NSPLITS 6
#define SLOT 36                // reduction slot stride (floats)
#define WS_STRIDE 448          // per-(split,n) ws slot (floats)

typedef __attribute__((address_space(3))) unsigned int lds_u32_t;
typedef __attribute__((address_space(1))) const unsigned int glb_u32_t;

__device__ __forceinline__ void gload16(const void* g, void* l) {
    __builtin_amdgcn_global_load_lds((glb_u32_t*)g, (lds_u32_t*)l, 16, 0, 0);
}

__global__ __launch_bounds__(NTHREADS, 3)
void siamfc_xcorr_part(const float* __restrict__ z, const float* __restrict__ x,
                       float* __restrict__ ws) {
    __shared__ __align__(16) float lds[4 * WBUF];   // [wave][buf], 21632 B

    const int tid  = threadIdx.x;
    const int lane = tid & 63;
    const int w    = tid >> 6;          // wave 0/1
    const int bid  = blockIdx.x;
    const int n     = bid / NSPLITS;
    const int split = bid - n * NSPLITS;
    // splits 0-3: 44 channels (11 rounds); splits 4-5: 40 channels (10 rounds)
    const int cb0    = (split < 4) ? 44 * split : 176 + 40 * (split - 4);
    const int nround = (split < 4) ? 11 : 10;

    const int cc = lane & 1;            // channel within the wave's pair
    const int g  = (lane >> 1) & 1;     // col half: cols 10g + o
    const int t  = (lane >> 2) & 7;     // 0..7, t==7 idle in compute
    const int h  = (lane >> 5) & 1;     // z rows 3h..3h+2
    const bool active = (t < 7);

    const float4* xg4 = (const float4*)x + (size_t)n * (256 * 169);
    const float2* zg2 = (const float2*)z + (size_t)n * (256 * 18);

    float* wbase = lds + w * (2 * WBUF);

    // 6 per-wave gload_lds for round r (wave's 2 channels = 338 contiguous quads)
    auto issue = [&](int r, int b) {
        const float4* xsrc = xg4 + (size_t)(cb0 + 4 * r + 2 * w) * 169;
        float* xb = wbase + b * WBUF;
        #pragma unroll
        for (int k = 0; k < 5; ++k)                   // quads k*64 + lane
            gload16(xsrc + k * 64 + lane, xb + (size_t)(k * 64) * 4);
        if (lane < 18)                                // quads 320..337
            gload16(xsrc + 320 + lane, xb + (size_t)320 * 4);
    };

    auto zload = [&](int r, float2 (&zq)[9]) {
        const float2* zp = zg2 + (size_t)(cb0 + 4 * r + 2 * w + cc) * 18 + 9 * h;
        #pragma unroll
        for (int e = 0; e < 9; ++e) zq[e] = zp[e];
    };

    float acc[33];
    #pragma unroll
    for (int v = 0; v < 33; ++v) acc[v] = 0.f;

    float2 zqA[9], zqB[9];

    issue(0, 0);
    zload(0, zqA);

    // one round: consume zuse/buf(r&1); prefetch x(r+1) DMA + z(r+1) into zpre
    auto round_body = [&](int r, float2 (&zuse)[9], float2 (&zpre)[9]) {
        if (r + 1 < nround) {
            issue(r + 1, (r + 1) & 1);
            asm volatile("s_waitcnt vmcnt(6)" ::: "memory");  // x(r), z(r) done
            zload(r + 1, zpre);        // in flight under compute(r)
        } else {
            asm volatile("s_waitcnt vmcnt(0)" ::: "memory");
        }
        if (active) {
            const float* xcb = wbase + (r & 1) * WBUF + cc * 676;
            float zv[3][6];
            #pragma unroll
            for (int e = 0; e < 9; ++e) {
                zv[e / 3][2 * (e % 3)]     = zuse[e].x;
                zv[e / 3][2 * (e % 3) + 1] = zuse[e].y;
            }
            #pragma unroll
            for (int m = 0; m < 5; ++m) {                // x rows 3t+3h+m
                const int row = 3 * t + 3 * h + m;       // <= 25
                const float2* rp = (const float2*)xcb + 13 * row + 5 * g;
                float xr[16];                            // row floats 10g..10g+15
                #pragma unroll
                for (int s = 0; s < 8; ++s) {
                    float2 q = rp[s];
                    xr[2 * s] = q.x; xr[2 * s + 1] = q.y;
                }
                #pragma unroll
                for (int zr = 0; zr < 3; ++zr) {
                    const int a = m - zr;                // output row 3t+a
                    if (a >= 0 && a < 3) {
                        #pragma unroll
                        for (int j = 0; j < 6; ++j)
                            #pragma unroll
                            for (int o = 0; o < 11; ++o) // out col 10g+o
                                acc[a * 11 + o] = fmaf(zv[zr][j], xr[o + j], acc[a * 11 + o]);
                    }
                }
            }
        }
    };

    #pragma unroll 1
    for (int r = 0; r + 1 < nround; r += 2) {
        round_body(r,     zqA, zqB);
        round_body(r + 1, zqB, zqA);
    }
    if (nround & 1)
        round_body(nround - 1, zqA, zqB);   // nround odd: last round even -> zqA

    // ---- in-wave folds: cc (lane bit0), h (lane bit5)
    #pragma unroll
    for (int v = 0; v < 33; ++v) {
        acc[v] += __shfl_xor(acc[v], 1, 64);
        acc[v] += __shfl_xor(acc[v], 32, 64);
    }

    // RACE FIX: both waves must finish ALL compute (staging LDS reads) before
    // either writes reduction slots, which alias wave-0's staging buffer.
    __syncthreads();

    // ---- cross-wave fold via LDS (reuse staging space)
    if (active && cc == 0 && h == 0) {
        float* wsl = lds + (size_t)(w * 14 + t * 2 + g) * SLOT;
        #pragma unroll
        for (int v = 0; v < 33; ++v) wsl[v] = acc[v];
    }
    __syncthreads();

    // ---- plain store of this split's 441 partials (no atomics, no memset)
    float* wp = ws + (size_t)(split * 256 + n) * WS_STRIDE;
    for (int o = tid; o < OH * OW; o += NTHREADS) {
        int row = o / OW, c = o - row * OW;
        int tt = row / 3, a = row - tt * 3;
        int gg = (c >= 11) ? 1 : 0;
        int vi = a * 11 + (c - 10 * gg);
        wp[o] = lds[(      tt * 2 + gg) * SLOT + vi]
              + lds[(14 +  tt * 2 + gg) * SLOT + vi];
    }
}

__global__ __launch_bounds__(WS_STRIDE, 4)
void siamfc_reduce(const float* __restrict__ ws, float* __restrict__ out) {
    const int n = blockIdx.x;
    const int o = threadIdx.x;
    if (o >= OH * OW) return;
    float s = 0.f;
    #pragma unroll
    for (int sp = 0; sp < NSPLITS; ++sp)
        s += ws[(size_t)(sp * 256 + n) * WS_STRIDE + o];
    out[(size_t)n * (OH * OW) + o] = s;
}

extern "C" void kernel_launch(void* const* d_in, const int* in_sizes, int n_in,
                              void* d_out, int out_size, void* d_ws, size_t ws_size,
                              hipStream_t stream) {
    const float* z = (const float*)d_in[0];
    const float* x = (const float*)d_in[1];
    float* out = (float*)d_out;
    float* wsp = (float*)d_ws;
    siamfc_xcorr_part<<<dim3(256 * NSPLITS), dim3(NTHREADS), 0, stream>>>(z, x, wsp);
    siamfc_reduce<<<dim3(256), dim3(WS_STRIDE), 0, stream>>>(wsp, out);
}